// Round 2
// baseline (594.097 us; speedup 1.0000x reference)
//
#include <hip/hip_runtime.h>
#include <hip/hip_bf16.h>
#include <hip/hip_fp16.h>

#define T_SEQ 4096
#define CDIM  768
#define BDIM  8
#define MROWS (BDIM * T_SEQ)   // 32768
#define NKVR  (3 * CDIM)       // 2304
#define CHL   32               // chunk length (half a raster row)
#define NCH   (T_SEQ / CHL)    // 128 chunks
#define BC    (BDIM * CDIM)    // 6144 independent recurrences
#define NKT   (CDIM / 64)      // 12 K-tiles of 64

typedef __attribute__((ext_vector_type(8))) short   short8;
typedef __attribute__((ext_vector_type(4))) float   floatx4;
typedef unsigned short ushort_t;
typedef unsigned int   uint_t;
struct ushort4_t { ushort_t x, y, z, w; };

__device__ __forceinline__ ushort_t f2b(float f) {
    __hip_bfloat16 h = __float2bfloat16(f);
    return *(ushort_t*)&h;
}
__device__ __forceinline__ float b2f(ushort_t s) {
    __hip_bfloat16 h;
    *(ushort_t*)&h = s;
    return __bfloat162float(h);
}
__device__ __forceinline__ ushort_t f2h(float f) {
    __half h = __float2half(f);
    return *(ushort_t*)&h;
}
__device__ __forceinline__ float h2f(ushort_t s) {
    __half h;
    *(ushort_t*)&h = s;
    return __half2float(h);
}

__device__ __forceinline__ void gload_lds16(const void* g, void* l) {
    __builtin_amdgcn_global_load_lds(
        (const __attribute__((address_space(1))) void*)g,
        (__attribute__((address_space(3))) void*)l, 16, 0, 0);
}

// SHIFTS table: channel group i = c/32 gets shift (dy, dx); out[y][x] = in[y-dy][x-dx]
__constant__ int c_dy[24] = {0,0,1,-1,1,-1,1,-1,0,0,2,-2,2,-2,2,-2,2,1,2,1,-2,-1,-2,-1};
__constant__ int c_dx[24] = {1,-1,0,0,1,-1,-1,1,2,-2,0,0,2,-2,-2,2,1,2,-1,-2,1,2,-1,-2};

// ---------------------------------------------------------------- weights -> bf16
__global__ void cvt_weights(const float* __restrict__ kw, const float* __restrict__ vw,
                            const float* __restrict__ rw, const float* __restrict__ ow,
                            ushort_t* __restrict__ wkvr, ushort_t* __restrict__ wo) {
    int i = blockIdx.x * 256 + threadIdx.x;
    if (i < CDIM * CDIM) {
        wkvr[i]                   = f2b(kw[i]);
        wkvr[i + CDIM * CDIM]     = f2b(vw[i]);
        wkvr[i + 2 * CDIM * CDIM] = f2b(rw[i]);
        wo[i]                     = f2b(ow[i]);
    }
}

// ------------------------------------------------- shift + zigzag reorder + bf16
__global__ void shift_zigzag(const float* __restrict__ x, ushort_t* __restrict__ xs) {
    size_t i = (size_t)blockIdx.x * 256 + threadIdx.x;   // over MROWS*CDIM/4
    if (i >= (size_t)MROWS * (CDIM / 4)) return;
    int c4 = (int)(i % (CDIM / 4)) * 4;
    size_t bt = i / (CDIM / 4);
    int tz = (int)(bt % T_SEQ);
    int b  = (int)(bt / T_SEQ);
    int r = tz >> 6, pos = tz & 63;
    int xcol = (r & 1) ? (63 - pos) : pos;
    int g = c4 >> 5;
    int ys = r - c_dy[g];
    int xsrc = xcol - c_dx[g];
    float4 val = {0.f, 0.f, 0.f, 0.f};
    if ((unsigned)ys < 64u && (unsigned)xsrc < 64u)
        val = *(const float4*)(x + ((size_t)b * T_SEQ + (size_t)(ys * 64 + xsrc)) * CDIM + c4);
    ushort4_t o;
    o.x = f2b(val.x); o.y = f2b(val.y); o.z = f2b(val.z); o.w = f2b(val.w);
    *(ushort4_t*)(xs + bt * CDIM + c4) = o;
}

// ---------------------------------------------------------------- bf16 MFMA GEMM
// 256x256 tile, BK=64, 512 threads (8 waves, 2M x 4N; per-wave 128x64 output).
// 8-phase schedule (2 K-tiles / 8 phases), counted vmcnt(6) once per K-tile
// (never 0 in steady state), raw s_barrier + lgkmcnt(0) + sched_barrier(0)
// per phase, setprio(1) around each 16-MFMA cluster.
// LDS: 2 buffers x 4 half-tile regions {A0,A1,B0,B1} x 16 KiB = 128 KiB.
// Staging: linear LDS dest (global_load_lds requirement), pre-swizzled global
// source: chunk slot s holds global chunk s^(row&7); reads un-swizzle -> 2-way
// bank aliasing (free). Half-tile issue schedule (region retired before the
// kt+2 prefetch into it can land):
//   phase0: A1(kt+1)->buf^1   (buf^1 not read during kt at all)
//   phase1: B0(kt+2)->buf     (B fully read into regs at phase0)
//   phase2: B1(kt+2)->buf
//   phase3: A0(kt+2)->buf     (issued after this phase's last A read)
// Prologue: issue 7 half-tiles {B0,B1,A0,A1}(0)+{B0,B1,A0}(1), vmcnt(6), barrier.
// vmcnt ledger (steady state, per wave): at phase-3 wait, outstanding =
// {A1(kt+1), B0(kt+2), B1(kt+2), A0(kt+2)} = 8 loads; vmcnt(6) retires
// A1(kt+1) and everything older, i.e. all 8 half-tiles of kt+1. Tail: kt=NKT-2
// drains to 0; kt=NKT-1 issues nothing.
// MODE 0 (NB=9): nb/3==0 -> k (fp16), ==1 -> v (fp16), ==2 -> sigmoid(r) bf16.
// MODE 1 (NB=3): fp32 out.

__device__ __forceinline__ void stage_half(const ushort_t* __restrict__ G,
                                           int grow0, int kk,
                                           ushort_t* dst, int t) {
#pragma unroll
    for (int i = 0; i < 2; i++) {
        const int ci = i * 512 + t;      // 1024 16B-chunks per half-tile
        const int r  = ci >> 3;          // 0..127 row in region
        const int sx = ci & 7;           // lds slot
        gload_lds16(G + (size_t)(grow0 + r) * CDIM + kk + ((sx ^ (r & 7)) << 3),
                    (void*)(dst + ci * 8));
    }
}

#define READ_A(MIBASE, K2)                                                  \
    _Pragma("unroll")                                                       \
    for (int j = 0; j < 4; j++) {                                           \
        const int rra = ((MIBASE) + j) * 16 + l15;                          \
        af[j] = *(const short8*)(aReg + rra * 64 +                          \
                                 ((((K2) * 4 + l4) ^ (rra & 7)) << 3));     \
    }

#define PHASE_TAIL(MIBASE, K2)                                              \
    __builtin_amdgcn_s_barrier();                                           \
    asm volatile("s_waitcnt lgkmcnt(0)" ::: "memory");                      \
    __builtin_amdgcn_sched_barrier(0);                                      \
    __builtin_amdgcn_s_setprio(1);                                          \
    _Pragma("unroll")                                                       \
    for (int j = 0; j < 4; j++) {                                           \
        _Pragma("unroll")                                                   \
        for (int ni = 0; ni < 4; ni++)                                      \
            acc[(MIBASE) + j][ni] = __builtin_amdgcn_mfma_f32_16x16x32_bf16(\
                af[j], bf[ni][K2], acc[(MIBASE) + j][ni], 0, 0, 0);         \
    }                                                                       \
    __builtin_amdgcn_s_setprio(0);                                          \
    __builtin_amdgcn_s_barrier();

template <int MODE, int NB>
__global__ __launch_bounds__(512, 2) void gemm_bt(
    const ushort_t* __restrict__ A, const ushort_t* __restrict__ Bw,
    ushort_t* __restrict__ kbuf, ushort_t* __restrict__ vbuf,
    ushort_t* __restrict__ out_sr, float* __restrict__ out_f) {
    __shared__ ushort_t lds[2][4][128 * 64];   // [buf][A0,A1,B0,B1][...] 128 KiB
    const int pid  = blockIdx.x;
    const int xcd  = pid & 7;
    const int sid  = pid >> 3;
    const int mb   = xcd + 8 * (sid / NB);   // all NB n-blocks of an m-strip on one XCD
    const int nb   = sid % NB;
    const int m0   = mb * 256;
    const int n0   = nb * 256;
    const int t    = threadIdx.x;
    const int lane = t & 63;
    const int wv   = t >> 6;                 // 0..7
    const int wr   = wv >> 2;                // A region (0: rows 0-127, 1: 128-255)
    const int wn   = (wv & 3) * 64;          // 0,64,128,192
    const int bRi  = 2 + (wn >> 7);          // B region index
    const int wn64 = wn & 64;                // row offset within B region
    const int l15  = lane & 15;
    const int l4   = lane >> 4;

    floatx4 acc[8][4];
#pragma unroll
    for (int i = 0; i < 8; i++)
#pragma unroll
        for (int j = 0; j < 4; j++) acc[i][j] = (floatx4){0.f, 0.f, 0.f, 0.f};

    // prologue: 7 half-tiles (K-tile 0 complete + 3 of K-tile 1)
    stage_half(Bw, n0,       0,  &lds[0][2][0], t);
    stage_half(Bw, n0 + 128, 0,  &lds[0][3][0], t);
    stage_half(A,  m0,       0,  &lds[0][0][0], t);
    stage_half(A,  m0 + 128, 0,  &lds[0][1][0], t);
    stage_half(Bw, n0,       64, &lds[1][2][0], t);
    stage_half(Bw, n0 + 128, 64, &lds[1][3][0], t);
    stage_half(A,  m0,       64, &lds[1][0][0], t);
    asm volatile("s_waitcnt vmcnt(6)" ::: "memory");
    __builtin_amdgcn_s_barrier();

#pragma unroll 2
    for (int kt = 0; kt < NKT; kt++) {
        const int p  = kt & 1;
        const int pn = p ^ 1;
        const ushort_t* aReg = &lds[p][wr][0];
        const ushort_t* bReg = &lds[p][bRi][0];
        short8 af[4];
        short8 bf[4][2];
        // ---- phase 0: all B frags + A(mi 0-3, k2=0); stage A1(kt+1)
#pragma unroll
        for (int ni = 0; ni < 4; ni++) {
            const int rrb = wn64 + ni * 16 + l15;
            const ushort_t* bp = bReg + rrb * 64;
            bf[ni][0] = *(const short8*)(bp + ((l4       ^ (rrb & 7)) << 3));
            bf[ni][1] = *(const short8*)(bp + (((4 + l4) ^ (rrb & 7)) << 3));
        }
        READ_A(0, 0)
        if (kt + 1 < NKT) stage_half(A, m0 + 128, (kt + 1) * 64, &lds[pn][1][0], t);
        PHASE_TAIL(0, 0)
        // ---- phase 1: A(mi 4-7, k2=0); stage B0(kt+2)
        READ_A(4, 0)
        if (kt + 2 < NKT) stage_half(Bw, n0, (kt + 2) * 64, &lds[p][2][0], t);
        PHASE_TAIL(4, 0)
        // ---- phase 2: A(mi 0-3, k2=1); stage B1(kt+2)
        READ_A(0, 1)
        if (kt + 2 < NKT) stage_half(Bw, n0 + 128, (kt + 2) * 64, &lds[p][3][0], t);
        PHASE_TAIL(0, 1)
        // ---- phase 3: A(mi 4-7, k2=1); stage A0(kt+2); counted vmcnt
        READ_A(4, 1)
        if (kt + 2 < NKT) stage_half(A, m0, (kt + 2) * 64, &lds[p][0][0], t);
        if (kt < NKT - 2) { asm volatile("s_waitcnt vmcnt(6)" ::: "memory"); }
        else              { asm volatile("s_waitcnt vmcnt(0)" ::: "memory"); }
        PHASE_TAIL(4, 1)
    }

    const int region = (MODE == 0) ? (nb / 3) : 0;
    const int ncb = n0 - region * CDIM;
#pragma unroll
    for (int mi = 0; mi < 8; mi++) {
#pragma unroll
        for (int ni = 0; ni < 4; ni++) {
            const int nc = ncb + wn + ni * 16 + l15;
#pragma unroll
            for (int r = 0; r < 4; r++) {
                const int mg = m0 + wr * 128 + mi * 16 + l4 * 4 + r;
                float val = acc[mi][ni][r];
                if (MODE == 0) {
                    if (region == 0)
                        kbuf[(size_t)mg * CDIM + nc] = f2h(val);
                    else if (region == 1)
                        vbuf[(size_t)mg * CDIM + nc] = f2h(val);
                    else
                        out_sr[(size_t)mg * CDIM + nc] =
                            f2b(1.0f / (1.0f + __expf(-val)));
                } else {
                    out_f[(size_t)mg * CDIM + nc] = val;
                }
            }
        }
    }
}

// ------------------------------------------------------------- WKV chunked scan
// Recurrence: P' = e^w P + e^k v ; state max-normalized as (p,q,o).
// kb / vb: separate fp16 planes (row, c). vb's value is overwritten with y by
// the pass-0 replay (contiguous 2B stores, no partial-line amplification).
// PASS 0 sequence = zigzag row order (buffer row order).
// PASS 1 sequence = raster order; CHL=32 chunk remap (verified):
//   pass-1 chunk ch's rows form pass-2 chunk idx2 = (ch&2) ? ch^1 : ch,
//   traversed in reverse iff (ch>>1)&1.

// Phase A (pass 0): per-chunk local summary from empty state.
__global__ __launch_bounds__(256) void wkv_chunk_sum0(
    const ushort_t* __restrict__ kb, const ushort_t* __restrict__ vb,
    const float* __restrict__ sd,
    float* __restrict__ sumP, float* __restrict__ sumQ, float* __restrict__ sumO) {
    int gid = blockIdx.x * 256 + threadIdx.x;
    int bc = gid % BC;
    int ch = gid / BC;
    int b = bc / CDIM, c = bc % CDIM;
    const float w = sd[c] * (1.0f / (float)T_SEQ);
    const size_t base = ((size_t)b * T_SEQ + ch * CHL) * CDIM + c;
    const ushort_t* kp = kb + base;
    const ushort_t* vp = vb + base;
    float p = 0.f, q = 0.f, o = -1e38f;
#pragma unroll 8
    for (int i = 0; i < CHL; i++) {
        float kt = h2f(kp[(size_t)i * CDIM]), vt = h2f(vp[(size_t)i * CDIM]);
        float wo_ = w + o;
        float no2 = fmaxf(wo_, kt);
        float A2 = __expf(wo_ - no2), B2 = __expf(kt - no2);
        p = A2 * p + B2 * vt;
        q = A2 * q + B2;
        o = no2;
    }
    size_t idx = (size_t)ch * BC + bc;
    sumP[idx] = p; sumQ[idx] = q; sumO[idx] = o;
}

// Phase B: sequential combine of chunk summaries; writes incoming state per chunk.
__global__ __launch_bounds__(256) void wkv_chunk_scan(
    const float* __restrict__ sumP, const float* __restrict__ sumQ,
    const float* __restrict__ sumO,
    float* __restrict__ inP, float* __restrict__ inQ, float* __restrict__ inO,
    const float* __restrict__ sd, int pass) {
    int bc = blockIdx.x * 256 + threadIdx.x;
    if (bc >= BC) return;
    int c = bc % CDIM;
    const float w = sd[pass * CDIM + c] * (1.0f / (float)T_SEQ);
    const float Lw = w * (float)CHL;
    float p = 0.f, q = 0.f, o = -1e38f;
    for (int ch = 0; ch < NCH; ch++) {
        size_t idx = (size_t)ch * BC + bc;
        inP[idx] = p; inQ[idx] = q; inO[idx] = o;
        float Pc = sumP[idx], Qc = sumQ[idx], Oc = sumO[idx];
        float ow_ = o + Lw;
        float no = fmaxf(ow_, Oc);
        float e1 = __expf(ow_ - no), e2 = __expf(Oc - no);
        p = e1 * p + e2 * Pc;
        q = e1 * q + e2 * Qc;
        o = no;
    }
}

// Phase C fused: replay pass-1 chunk (y -> vb, y kept in regs, FULLY unrolled
// so k/y stay in registers), then pass-2 chunk summary over the same rows in
// raster traversal.
__global__ __launch_bounds__(256) void wkv_replay0_sum1(
    const ushort_t* __restrict__ kb, ushort_t* __restrict__ vb,
    const float* __restrict__ sd, const float* __restrict__ sf,
    const float* __restrict__ inP, const float* __restrict__ inQ,
    const float* __restrict__ inO,
    float* __restrict__ sumP, float* __restrict__ sumQ, float* __restrict__ sumO) {
    int gid = blockIdx.x * 256 + threadIdx.x;
    int bc = gid % BC;
    int ch = gid / BC;
    int b = bc / CDIM, c = bc % CDIM;
    const float w1 = sd[c] * (1.0f / (float)T_SEQ);
    const float u1 = sf[c] * (1.0f / (float)T_SEQ);
    const size_t base = ((size_t)b * T_SEQ + ch * CHL) * CDIM + c;
    const ushort_t* kp = kb + base;
    ushort_t* vp = vb + base;
    size_t idx = (size_t)ch * BC + bc;
    float p = inP[idx], q = inQ[idx], o = inO[idx];
    float yv[CHL];
    float kvk[CHL];
#pragma unroll
    for (int i = 0; i < CHL; i++) {
        float kt = h2f(kp[(size_t)i * CDIM]), vt = h2f(vp[(size_t)i * CDIM]);
        kvk[i] = kt;
        float uk = u1 + kt;
        float no = fmaxf(o, uk);
        float Ae = __expf(o - no), Be = __expf(uk - no);
        float y = (Ae * p + Be * vt) / (Ae * q + Be);
        float wo_ = w1 + o;
        float no2 = fmaxf(wo_, kt);
        float A2 = __expf(wo_ - no2), B2 = __expf(kt - no2);
        p = A2 * p + B2 * vt;
        q = A2 * q + B2;
        o = no2;
        yv[i] = y;
        vp[(size_t)i * CDIM] = f2h(y);   // overwrite v with y
    }
    // pass-2 summary over same rows; raster traversal
    const float w2 = sd[CDIM + c] * (1.0f / (float)T_SEQ);
    float p2 = 0.f, q2 = 0.f, o2 = -1e38f;
    const bool rev = (ch >> 1) & 1;
#pragma unroll
    for (int j = 0; j < CHL; j++) {
        int i = rev ? (CHL - 1 - j) : j;
        float kt = kvk[i], vt = yv[i];
        float wo_ = w2 + o2;
        float no2 = fmaxf(wo_, kt);
        float A2 = __expf(wo_ - no2), B2 = __expf(kt - no2);
        p2 = A2 * p2 + B2 * vt;
        q2 = A2 * q2 + B2;
        o2 = no2;
    }
    size_t idx2 = (size_t)((ch & 2) ? (ch ^ 1) : ch) * BC + bc;
    sumP[idx2] = p2; sumQ[idx2] = q2; sumO[idx2] = o2;
}

// Phase C (pass 1): replay raster-order chunk ch, emit a2 = bf16(y * sr).
__global__ __launch_bounds__(256) void wkv_replay1(
    const ushort_t* __restrict__ kb, const ushort_t* __restrict__ vb,
    const ushort_t* __restrict__ srb, ushort_t* __restrict__ a2,
    const float* __restrict__ sd, const float* __restrict__ sf,
    const float* __restrict__ inP, const float* __restrict__ inQ,
    const float* __restrict__ inO) {
    int gid = blockIdx.x * 256 + threadIdx.x;
    int bc = gid % BC;
    int ch = gid / BC;
    int b = bc / CDIM, c = bc % CDIM;
    const float w = sd[CDIM + c] * (1.0f / (float)T_SEQ);
    const float u = sf[CDIM + c] * (1.0f / (float)T_SEQ);
    size_t base = (size_t)b * T_SEQ * CDIM + c;
    size_t idx = (size_t)ch * BC + bc;
    float p = inP[idx], q = inQ[idx], o = inO[idx];
    const int r = ch >> 1;
    const int pos0 = (ch & 1) * CHL;
#pragma unroll 8
    for (int i = 0; i < CHL; i++) {
        int pos = pos0 + i;
        int col = (r & 1) ? (63 - pos) : pos;
        size_t off = base + (size_t)(r * 64 + col) * CDIM;
        float kt = h2f(kb[off]), vt = h2f(vb[off]);
        float uk = u + kt;
        float no = fmaxf(o, uk);
        float Ae = __expf(o - no), Be = __expf(uk - no);
        float y = (Ae * p + Be * vt) / (Ae * q + Be);
        float wo_ = w + o;
        float no2 = fmaxf(wo_, kt);
        float A2 = __expf(wo_ - no2), B2 = __expf(kt - no2);
        p = A2 * p + B2 * vt;
        q = A2 * q + B2;
        o = no2;
        a2[off] = f2b(y * b2f(srb[off]));
    }
}

// ----------------------------------------------------------------------- launch
extern "C" void kernel_launch(void* const* d_in, const int* in_sizes, int n_in,
                              void* d_out, int out_size, void* d_ws, size_t ws_size,
                              hipStream_t stream) {
    (void)in_sizes; (void)n_in; (void)out_size; (void)ws_size;
    const float* x  = (const float*)d_in[0];
    const float* kw = (const float*)d_in[1];
    const float* vw = (const float*)d_in[2];
    const float* rw = (const float*)d_in[3];
    const float* ow = (const float*)d_in[4];
    const float* sd = (const float*)d_in[5];
    const float* sf = (const float*)d_in[6];
    float* out = (float*)d_out;

    char* ws = (char*)d_ws;
    size_t off = 0;
    auto alloc = [&](size_t bytes) -> void* {
        void* p = ws + off;
        off += (bytes + 255) & ~(size_t)255;
        return p;
    };
    ushort_t* xs   = (ushort_t*)alloc((size_t)MROWS * CDIM * 2);  // reused as a2
    ushort_t* kb   = (ushort_t*)alloc((size_t)MROWS * CDIM * 2);  // k fp16
    ushort_t* vb   = (ushort_t*)alloc((size_t)MROWS * CDIM * 2);  // v / y fp16
    ushort_t* srb  = (ushort_t*)alloc((size_t)MROWS * CDIM * 2);  // bf16
    ushort_t* wkvr = (ushort_t*)alloc((size_t)NKVR * CDIM * 2);
    ushort_t* wo   = (ushort_t*)alloc((size_t)CDIM * CDIM * 2);
    float*    sumP = (float*)   alloc((size_t)NCH * BC * 4);
    float*    sumQ = (float*)   alloc((size_t)NCH * BC * 4);
    float*    sumO = (float*)   alloc((size_t)NCH * BC * 4);
    float*    inP  = (float*)   alloc((size_t)NCH * BC * 4);
    float*    inQ  = (float*)   alloc((size_t)NCH * BC * 4);
    float*    inO  = (float*)   alloc((size_t)NCH * BC * 4);

    cvt_weights<<<(CDIM * CDIM + 255) / 256, 256, 0, stream>>>(kw, vw, rw, ow, wkvr, wo);
    shift_zigzag<<<(int)(((size_t)MROWS * (CDIM / 4) + 255) / 256), 256, 0, stream>>>(x, xs);
    gemm_bt<0, 9><<<(MROWS / 256) * (NKVR / 256), 512, 0, stream>>>(
        xs, wkvr, kb, vb, srb, nullptr);

    const int nwkv = NCH * BC;  // 786432 threads
    wkv_chunk_sum0<<<nwkv / 256, 256, 0, stream>>>(kb, vb, sd, sumP, sumQ, sumO);
    wkv_chunk_scan<<<(BC + 255) / 256, 256, 0, stream>>>(sumP, sumQ, sumO,
                                                         inP, inQ, inO, sd, 0);
    wkv_replay0_sum1<<<nwkv / 256, 256, 0, stream>>>(kb, vb, sd, sf,
                                                     inP, inQ, inO, sumP, sumQ, sumO);
    wkv_chunk_scan<<<(BC + 255) / 256, 256, 0, stream>>>(sumP, sumQ, sumO,
                                                         inP, inQ, inO, sd, 1);
    wkv_replay1<<<nwkv / 256, 256, 0, stream>>>(kb, vb, srb, xs,
                                                sd, sf, inP, inQ, inO);

    gemm_bt<1, 3><<<(MROWS / 256) * (CDIM / 256), 512, 0, stream>>>(
        xs, wo, nullptr, nullptr, nullptr, out);
}

// Round 3
// 566.571 us; speedup vs baseline: 1.0486x; 1.0486x over previous
//
#include <hip/hip_runtime.h>
#include <hip/hip_bf16.h>
#include <hip/hip_fp16.h>

#define T_SEQ 4096
#define CDIM  768
#define BDIM  8
#define MROWS (BDIM * T_SEQ)   // 32768
#define NKVR  (3 * CDIM)       // 2304
#define CHL   32               // chunk length (half a raster row)
#define NCH   (T_SEQ / CHL)    // 128 chunks
#define BC    (BDIM * CDIM)    // 6144 independent recurrences

typedef __attribute__((ext_vector_type(8))) short   short8;
typedef __attribute__((ext_vector_type(4))) float   floatx4;
typedef unsigned short ushort_t;
typedef unsigned int   uint_t;
struct ushort4_t { ushort_t x, y, z, w; };

__device__ __forceinline__ ushort_t f2b(float f) {
    __hip_bfloat16 h = __float2bfloat16(f);
    return *(ushort_t*)&h;
}
__device__ __forceinline__ float b2f(ushort_t s) {
    __hip_bfloat16 h;
    *(ushort_t*)&h = s;
    return __bfloat162float(h);
}
__device__ __forceinline__ ushort_t f2h(float f) {
    __half h = __float2half(f);
    return *(ushort_t*)&h;
}
__device__ __forceinline__ float h2f(ushort_t s) {
    __half h;
    *(ushort_t*)&h = s;
    return __half2float(h);
}

__device__ __forceinline__ void gload_lds16(const void* g, void* l) {
    __builtin_amdgcn_global_load_lds(
        (const __attribute__((address_space(1))) void*)g,
        (__attribute__((address_space(3))) void*)l, 16, 0, 0);
}

// SHIFTS table: channel group i = c/32 gets shift (dy, dx); out[y][x] = in[y-dy][x-dx]
__constant__ int c_dy[24] = {0,0,1,-1,1,-1,1,-1,0,0,2,-2,2,-2,2,-2,2,1,2,1,-2,-1,-2,-1};
__constant__ int c_dx[24] = {1,-1,0,0,1,-1,-1,1,2,-2,0,0,2,-2,-2,2,1,2,-1,-2,1,2,-1,-2};

// ---------------------------------------------------------------- weights -> bf16
__global__ void cvt_weights(const float* __restrict__ kw, const float* __restrict__ vw,
                            const float* __restrict__ rw, const float* __restrict__ ow,
                            ushort_t* __restrict__ wkvr, ushort_t* __restrict__ wo) {
    int i = blockIdx.x * 256 + threadIdx.x;
    if (i < CDIM * CDIM) {
        wkvr[i]                   = f2b(kw[i]);
        wkvr[i + CDIM * CDIM]     = f2b(vw[i]);
        wkvr[i + 2 * CDIM * CDIM] = f2b(rw[i]);
        wo[i]                     = f2b(ow[i]);
    }
}

// ------------------------------------------------- shift + zigzag reorder + bf16
__global__ void shift_zigzag(const float* __restrict__ x, ushort_t* __restrict__ xs) {
    size_t i = (size_t)blockIdx.x * 256 + threadIdx.x;   // over MROWS*CDIM/4
    if (i >= (size_t)MROWS * (CDIM / 4)) return;
    int c4 = (int)(i % (CDIM / 4)) * 4;
    size_t bt = i / (CDIM / 4);
    int tz = (int)(bt % T_SEQ);
    int b  = (int)(bt / T_SEQ);
    int r = tz >> 6, pos = tz & 63;
    int xcol = (r & 1) ? (63 - pos) : pos;
    int g = c4 >> 5;
    int ys = r - c_dy[g];
    int xsrc = xcol - c_dx[g];
    float4 val = {0.f, 0.f, 0.f, 0.f};
    if ((unsigned)ys < 64u && (unsigned)xsrc < 64u)
        val = *(const float4*)(x + ((size_t)b * T_SEQ + (size_t)(ys * 64 + xsrc)) * CDIM + c4);
    ushort4_t o;
    o.x = f2b(val.x); o.y = f2b(val.y); o.z = f2b(val.z); o.w = f2b(val.w);
    *(ushort4_t*)(xs + bt * CDIM + c4) = o;
}

// ---------------------------------------------------------------- bf16 MFMA GEMM
// PROVEN round-0 structure: C[m,n] = sum_k A[m,k] * W[n,k]; 128x128 tile, BK=64
// (12 barriers), 256 thr, 3 blocks/CU. 8-phase 256^2 port regressed (r2:
// 174.7us, MfmaUtil 28%, 1 blk/CU — phase reads serialize with MFMA between
// block-wide barriers); reverted. Kept from r2: kb/vb split output planes
// (verified: WRITE_SIZE 198.7->156.7 MB, removes stride-4 2B store
// amplification).
// XCD swizzle: all NB n-blocks of an m-strip share one XCD (L2-hot A + W).
// Staging: thread t loads global chunk gc = (t&7)^(row&7) into LDS slot t&7
// (global_load_lds requires lane-contiguous LDS dest); reads un-swizzle ->
// 2-way bank aliasing (free).
// MODE 0 (NB=18): nb/6==0 -> k (fp16) -> kbuf, ==1 -> v (fp16) -> vbuf,
// ==2 -> sigmoid(r) bf16 -> out_sr. MODE 1 (NB=6): fp32 out.
template <int MODE, int NB>
__global__ __launch_bounds__(256, 3) void gemm_bt(
    const ushort_t* __restrict__ A, const ushort_t* __restrict__ Bw,
    ushort_t* __restrict__ kbuf, ushort_t* __restrict__ vbuf,
    ushort_t* __restrict__ out_sr, float* __restrict__ out_f) {
    __shared__ ushort_t As[128 * 64];
    __shared__ ushort_t Bs[128 * 64];
    const int p    = blockIdx.x;
    const int xcd  = p & 7;
    const int s    = p >> 3;
    const int mb   = xcd + 8 * (s / NB);
    const int nb   = s % NB;
    const int m0   = mb * 128;
    const int n0   = nb * 128;
    const int t    = threadIdx.x;
    const int lane = t & 63;
    const int wv   = t >> 6;
    const int wm   = (wv & 1) * 64;
    const int wn   = (wv >> 1) * 64;
    const int srow = t >> 3;   // 0..31
    const int sch  = t & 7;    // lds slot chunk
    const int l15  = lane & 15;
    const int l4   = lane >> 4;

    floatx4 acc[4][4];
#pragma unroll
    for (int i = 0; i < 4; i++)
#pragma unroll
        for (int j = 0; j < 4; j++) acc[i][j] = (floatx4){0.f, 0.f, 0.f, 0.f};

    for (int kk = 0; kk < CDIM; kk += 64) {
        __syncthreads();
#pragma unroll
        for (int j = 0; j < 4; j++) {
            const int rowA = 32 * j + srow;
            const int gc   = sch ^ (rowA & 7);
            gload_lds16(A  + (size_t)(m0 + rowA) * CDIM + kk + gc * 8,
                        (void*)(As + j * 2048 + t * 8));
            gload_lds16(Bw + (size_t)(n0 + rowA) * CDIM + kk + gc * 8,
                        (void*)(Bs + j * 2048 + t * 8));
        }
        __syncthreads();
#pragma unroll
        for (int k2 = 0; k2 < 2; k2++) {
            short8 af[4], bfv[4];
#pragma unroll
            for (int mi = 0; mi < 4; mi++) {
                int ra = wm + mi * 16 + l15;
                int c  = k2 * 4 + l4;
                af[mi] = *(const short8*)(As + ra * 64 + ((c ^ (ra & 7)) << 3));
            }
#pragma unroll
            for (int ni = 0; ni < 4; ni++) {
                int rb = wn + ni * 16 + l15;
                int c  = k2 * 4 + l4;
                bfv[ni] = *(const short8*)(Bs + rb * 64 + ((c ^ (rb & 7)) << 3));
            }
#pragma unroll
            for (int mi = 0; mi < 4; mi++)
#pragma unroll
                for (int ni = 0; ni < 4; ni++)
                    acc[mi][ni] = __builtin_amdgcn_mfma_f32_16x16x32_bf16(
                        af[mi], bfv[ni], acc[mi][ni], 0, 0, 0);
        }
    }

    const int region = (MODE == 0) ? (nb / 6) : 0;
    const int ncb = n0 - region * CDIM;
#pragma unroll
    for (int mi = 0; mi < 4; mi++) {
#pragma unroll
        for (int ni = 0; ni < 4; ni++) {
            int nc = ncb + wn + ni * 16 + l15;
#pragma unroll
            for (int r = 0; r < 4; r++) {
                int mg = m0 + wm + mi * 16 + l4 * 4 + r;
                float val = acc[mi][ni][r];
                if (MODE == 0) {
                    if (region == 0)
                        kbuf[(size_t)mg * CDIM + nc] = f2h(val);
                    else if (region == 1)
                        vbuf[(size_t)mg * CDIM + nc] = f2h(val);
                    else
                        out_sr[(size_t)mg * CDIM + nc] =
                            f2b(1.0f / (1.0f + __expf(-val)));
                } else {
                    out_f[(size_t)mg * CDIM + (n0 + wn + ni * 16 + l15)] = val;
                }
            }
        }
    }
}

// ------------------------------------------------------------- WKV chunked scan
// Recurrence: P' = e^w P + e^k v ; state max-normalized as (p,q,o).
// kb / vb: separate fp16 planes (row, c). vb's value is overwritten with y by
// the pass-0 replay (contiguous 2B stores, no partial-line amplification).
// PASS 0 sequence = zigzag row order (buffer row order).
// PASS 1 sequence = raster order; CHL=32 chunk remap (verified):
//   pass-1 chunk ch's rows form pass-2 chunk idx2 = (ch&2) ? ch^1 : ch,
//   traversed in reverse iff (ch>>1)&1.

// Phase A (pass 0): per-chunk local summary from empty state.
__global__ __launch_bounds__(256) void wkv_chunk_sum0(
    const ushort_t* __restrict__ kb, const ushort_t* __restrict__ vb,
    const float* __restrict__ sd,
    float* __restrict__ sumP, float* __restrict__ sumQ, float* __restrict__ sumO) {
    int gid = blockIdx.x * 256 + threadIdx.x;
    int bc = gid % BC;
    int ch = gid / BC;
    int b = bc / CDIM, c = bc % CDIM;
    const float w = sd[c] * (1.0f / (float)T_SEQ);
    const size_t base = ((size_t)b * T_SEQ + ch * CHL) * CDIM + c;
    const ushort_t* kp = kb + base;
    const ushort_t* vp = vb + base;
    float p = 0.f, q = 0.f, o = -1e38f;
#pragma unroll 8
    for (int i = 0; i < CHL; i++) {
        float kt = h2f(kp[(size_t)i * CDIM]), vt = h2f(vp[(size_t)i * CDIM]);
        float wo_ = w + o;
        float no2 = fmaxf(wo_, kt);
        float A2 = __expf(wo_ - no2), B2 = __expf(kt - no2);
        p = A2 * p + B2 * vt;
        q = A2 * q + B2;
        o = no2;
    }
    size_t idx = (size_t)ch * BC + bc;
    sumP[idx] = p; sumQ[idx] = q; sumO[idx] = o;
}

// Phase B: sequential combine of chunk summaries; writes incoming state per chunk.
__global__ __launch_bounds__(256) void wkv_chunk_scan(
    const float* __restrict__ sumP, const float* __restrict__ sumQ,
    const float* __restrict__ sumO,
    float* __restrict__ inP, float* __restrict__ inQ, float* __restrict__ inO,
    const float* __restrict__ sd, int pass) {
    int bc = blockIdx.x * 256 + threadIdx.x;
    if (bc >= BC) return;
    int c = bc % CDIM;
    const float w = sd[pass * CDIM + c] * (1.0f / (float)T_SEQ);
    const float Lw = w * (float)CHL;
    float p = 0.f, q = 0.f, o = -1e38f;
    for (int ch = 0; ch < NCH; ch++) {
        size_t idx = (size_t)ch * BC + bc;
        inP[idx] = p; inQ[idx] = q; inO[idx] = o;
        float Pc = sumP[idx], Qc = sumQ[idx], Oc = sumO[idx];
        float ow_ = o + Lw;
        float no = fmaxf(ow_, Oc);
        float e1 = __expf(ow_ - no), e2 = __expf(Oc - no);
        p = e1 * p + e2 * Pc;
        q = e1 * q + e2 * Qc;
        o = no;
    }
}

// Phase C fused: replay pass-1 chunk (y -> vb, y kept in regs, FULLY unrolled
// so k/y stay in registers), then pass-2 chunk summary over the same rows in
// raster traversal.
__global__ __launch_bounds__(256) void wkv_replay0_sum1(
    const ushort_t* __restrict__ kb, ushort_t* __restrict__ vb,
    const float* __restrict__ sd, const float* __restrict__ sf,
    const float* __restrict__ inP, const float* __restrict__ inQ,
    const float* __restrict__ inO,
    float* __restrict__ sumP, float* __restrict__ sumQ, float* __restrict__ sumO) {
    int gid = blockIdx.x * 256 + threadIdx.x;
    int bc = gid % BC;
    int ch = gid / BC;
    int b = bc / CDIM, c = bc % CDIM;
    const float w1 = sd[c] * (1.0f / (float)T_SEQ);
    const float u1 = sf[c] * (1.0f / (float)T_SEQ);
    const size_t base = ((size_t)b * T_SEQ + ch * CHL) * CDIM + c;
    const ushort_t* kp = kb + base;
    ushort_t* vp = vb + base;
    size_t idx = (size_t)ch * BC + bc;
    float p = inP[idx], q = inQ[idx], o = inO[idx];
    float yv[CHL];
    float kvk[CHL];
#pragma unroll
    for (int i = 0; i < CHL; i++) {
        float kt = h2f(kp[(size_t)i * CDIM]), vt = h2f(vp[(size_t)i * CDIM]);
        kvk[i] = kt;
        float uk = u1 + kt;
        float no = fmaxf(o, uk);
        float Ae = __expf(o - no), Be = __expf(uk - no);
        float y = (Ae * p + Be * vt) / (Ae * q + Be);
        float wo_ = w1 + o;
        float no2 = fmaxf(wo_, kt);
        float A2 = __expf(wo_ - no2), B2 = __expf(kt - no2);
        p = A2 * p + B2 * vt;
        q = A2 * q + B2;
        o = no2;
        yv[i] = y;
        vp[(size_t)i * CDIM] = f2h(y);   // overwrite v with y
    }
    // pass-2 summary over same rows; raster traversal
    const float w2 = sd[CDIM + c] * (1.0f / (float)T_SEQ);
    float p2 = 0.f, q2 = 0.f, o2 = -1e38f;
    const bool rev = (ch >> 1) & 1;
#pragma unroll
    for (int j = 0; j < CHL; j++) {
        int i = rev ? (CHL - 1 - j) : j;
        float kt = kvk[i], vt = yv[i];
        float wo_ = w2 + o2;
        float no2 = fmaxf(wo_, kt);
        float A2 = __expf(wo_ - no2), B2 = __expf(kt - no2);
        p2 = A2 * p2 + B2 * vt;
        q2 = A2 * q2 + B2;
        o2 = no2;
    }
    size_t idx2 = (size_t)((ch & 2) ? (ch ^ 1) : ch) * BC + bc;
    sumP[idx2] = p2; sumQ[idx2] = q2; sumO[idx2] = o2;
}

// Phase C (pass 1): replay raster-order chunk ch, emit a2 = bf16(y * sr).
__global__ __launch_bounds__(256) void wkv_replay1(
    const ushort_t* __restrict__ kb, const ushort_t* __restrict__ vb,
    const ushort_t* __restrict__ srb, ushort_t* __restrict__ a2,
    const float* __restrict__ sd, const float* __restrict__ sf,
    const float* __restrict__ inP, const float* __restrict__ inQ,
    const float* __restrict__ inO) {
    int gid = blockIdx.x * 256 + threadIdx.x;
    int bc = gid % BC;
    int ch = gid / BC;
    int b = bc / CDIM, c = bc % CDIM;
    const float w = sd[CDIM + c] * (1.0f / (float)T_SEQ);
    const float u = sf[CDIM + c] * (1.0f / (float)T_SEQ);
    size_t base = (size_t)b * T_SEQ * CDIM + c;
    size_t idx = (size_t)ch * BC + bc;
    float p = inP[idx], q = inQ[idx], o = inO[idx];
    const int r = ch >> 1;
    const int pos0 = (ch & 1) * CHL;
#pragma unroll 8
    for (int i = 0; i < CHL; i++) {
        int pos = pos0 + i;
        int col = (r & 1) ? (63 - pos) : pos;
        size_t off = base + (size_t)(r * 64 + col) * CDIM;
        float kt = h2f(kb[off]), vt = h2f(vb[off]);
        float uk = u + kt;
        float no = fmaxf(o, uk);
        float Ae = __expf(o - no), Be = __expf(uk - no);
        float y = (Ae * p + Be * vt) / (Ae * q + Be);
        float wo_ = w + o;
        float no2 = fmaxf(wo_, kt);
        float A2 = __expf(wo_ - no2), B2 = __expf(kt - no2);
        p = A2 * p + B2 * vt;
        q = A2 * q + B2;
        o = no2;
        a2[off] = f2b(y * b2f(srb[off]));
    }
}

// ----------------------------------------------------------------------- launch
extern "C" void kernel_launch(void* const* d_in, const int* in_sizes, int n_in,
                              void* d_out, int out_size, void* d_ws, size_t ws_size,
                              hipStream_t stream) {
    (void)in_sizes; (void)n_in; (void)out_size; (void)ws_size;
    const float* x  = (const float*)d_in[0];
    const float* kw = (const float*)d_in[1];
    const float* vw = (const float*)d_in[2];
    const float* rw = (const float*)d_in[3];
    const float* ow = (const float*)d_in[4];
    const float* sd = (const float*)d_in[5];
    const float* sf = (const float*)d_in[6];
    float* out = (float*)d_out;

    char* ws = (char*)d_ws;
    size_t off = 0;
    auto alloc = [&](size_t bytes) -> void* {
        void* p = ws + off;
        off += (bytes + 255) & ~(size_t)255;
        return p;
    };
    ushort_t* xs   = (ushort_t*)alloc((size_t)MROWS * CDIM * 2);  // reused as a2
    ushort_t* kb   = (ushort_t*)alloc((size_t)MROWS * CDIM * 2);  // k fp16
    ushort_t* vb   = (ushort_t*)alloc((size_t)MROWS * CDIM * 2);  // v / y fp16
    ushort_t* srb  = (ushort_t*)alloc((size_t)MROWS * CDIM * 2);  // bf16
    ushort_t* wkvr = (ushort_t*)alloc((size_t)NKVR * CDIM * 2);
    ushort_t* wo   = (ushort_t*)alloc((size_t)CDIM * CDIM * 2);
    float*    sumP = (float*)   alloc((size_t)NCH * BC * 4);
    float*    sumQ = (float*)   alloc((size_t)NCH * BC * 4);
    float*    sumO = (float*)   alloc((size_t)NCH * BC * 4);
    float*    inP  = (float*)   alloc((size_t)NCH * BC * 4);
    float*    inQ  = (float*)   alloc((size_t)NCH * BC * 4);
    float*    inO  = (float*)   alloc((size_t)NCH * BC * 4);

    cvt_weights<<<(CDIM * CDIM + 255) / 256, 256, 0, stream>>>(kw, vw, rw, ow, wkvr, wo);
    shift_zigzag<<<(int)(((size_t)MROWS * (CDIM / 4) + 255) / 256), 256, 0, stream>>>(x, xs);
    gemm_bt<0, 18><<<(MROWS / 128) * (NKVR / 128), 256, 0, stream>>>(
        xs, wkvr, kb, vb, srb, nullptr);

    const int nwkv = NCH * BC;  // 786432 threads
    wkv_chunk_sum0<<<nwkv / 256, 256, 0, stream>>>(kb, vb, sd, sumP, sumQ, sumO);
    wkv_chunk_scan<<<(BC + 255) / 256, 256, 0, stream>>>(sumP, sumQ, sumO,
                                                         inP, inQ, inO, sd, 0);
    wkv_replay0_sum1<<<nwkv / 256, 256, 0, stream>>>(kb, vb, sd, sf,
                                                     inP, inQ, inO, sumP, sumQ, sumO);
    wkv_chunk_scan<<<(BC + 255) / 256, 256, 0, stream>>>(sumP, sumQ, sumO,
                                                         inP, inQ, inO, sd, 1);
    wkv_replay1<<<nwkv / 256, 256, 0, stream>>>(kb, vb, srb, xs,
                                                sd, sf, inP, inQ, inO);

    gemm_bt<1, 6><<<(MROWS / 128) * (CDIM / 128), 256, 0, stream>>>(
        xs, wo, nullptr, nullptr, nullptr, out);
}